// Round 5
// baseline (357.433 us; speedup 1.0000x reference)
//
#include <hip/hip_runtime.h>
#include <hip/hip_bf16.h>

typedef __hip_bfloat16 bf16;
typedef __attribute__((ext_vector_type(8))) short bf16x8;
typedef __attribute__((ext_vector_type(8))) unsigned short u16x8;
typedef __attribute__((ext_vector_type(4))) float f32x4;
typedef __attribute__((ext_vector_type(4))) int i32x4;
typedef __attribute__((ext_vector_type(4))) short s16x4;

__device__ __forceinline__ float b2f(unsigned short u) {
  return __uint_as_float(((unsigned)u) << 16);
}
__device__ __forceinline__ unsigned short f2b(float x) {
  bf16 h = __float2bfloat16(x);
  return *reinterpret_cast<unsigned short*>(&h);
}

// ============== passA: coarse hist of dst + global-atomic deg_out + dtype probe =======
// counts[0..M): dst buckets (counts[k*256+b]). deg_out via direct atomics (replaces
// the whole src-side scatter path: tmp2, second scan half, passD phase 1).
__global__ void k_passA(const int* __restrict__ src, const int* __restrict__ dst, int E,
                        int nbuck, int* __restrict__ counts,
                        const unsigned short* __restrict__ raw, int* __restrict__ flag,
                        int* __restrict__ degout) {
  if (blockIdx.x == 256) {
    __shared__ int sbad, snz;
    const int t = threadIdx.x;
    if (t == 0) { sbad = 0; snz = 0; }
    __syncthreads();
    const unsigned short u = raw[t];
    const float a = fabsf(b2f(u));
    if (!(a < 100.f)) atomicAdd(&sbad, 1);
    if (((t & 1) == 0) && u != 0) atomicAdd(&snz, 1);
    __syncthreads();
    if (t == 0) flag[0] = (sbad == 0 && snz > 0) ? 1 : 0;
    return;
  }
  extern __shared__ int lh1[];
  const int t = threadIdx.x;
  for (int k = t; k < nbuck; k += 256) lh1[k] = 0;
  __syncthreads();
  const int chunk = (E + 255) / 256;
  const int s = blockIdx.x * chunk;
  const int e = min(E, s + chunk);
  for (int i = s + t; i < e; i += 256) {
    atomicAdd(&lh1[dst[i] >> 8], 1);
    atomicAdd(&degout[src[i]], 1);
  }
  __syncthreads();
  for (int k = t; k < nbuck; k += 256) counts[k * 256 + blockIdx.x] = lh1[k];
}

// exclusive scan over M ints
__global__ void k_scan1(const int* __restrict__ a, int M, int* __restrict__ bsums) {
  __shared__ int sdata[256];
  int i = blockIdx.x * 256 + threadIdx.x;
  int v = (i < M) ? a[i] : 0;
  sdata[threadIdx.x] = v;
  __syncthreads();
  for (int s = 128; s > 0; s >>= 1) {
    if (threadIdx.x < s) sdata[threadIdx.x] += sdata[threadIdx.x + s];
    __syncthreads();
  }
  if (threadIdx.x == 0) bsums[blockIdx.x] = sdata[0];
}

__global__ void k_scan2(int* __restrict__ bsums, int nb, int* __restrict__ rowStart,
                        int N, int E) {
  __shared__ int s[1024];
  const int t = threadIdx.x;
  const int v = (t < nb) ? bsums[t] : 0;
  s[t] = v;
  __syncthreads();
  for (int off = 1; off < 1024; off <<= 1) {
    int u = (t >= off) ? s[t - off] : 0;
    __syncthreads();
    s[t] += u;
    __syncthreads();
  }
  if (t < nb) bsums[t] = s[t] - v;  // exclusive
  if (t == 0) rowStart[N] = E;
}

__global__ void k_scan3(int* __restrict__ a, int M, const int* __restrict__ bsums) {
  __shared__ int sdata[256];
  int i = blockIdx.x * 256 + threadIdx.x;
  int v = (i < M) ? a[i] : 0;
  sdata[threadIdx.x] = v;
  __syncthreads();
  for (int off = 1; off < 256; off <<= 1) {
    int t = (threadIdx.x >= off) ? sdata[threadIdx.x - off] : 0;
    __syncthreads();
    sdata[threadIdx.x] += t;
    __syncthreads();
  }
  if (i < M) a[i] = bsums[blockIdx.x] + sdata[threadIdx.x] - v;  // exclusive
}

// passC: dst scatter via LDS cursors — ZERO global atomics (src side now gone).
__global__ void k_passC(const int* __restrict__ src, const int* __restrict__ dst, int E,
                        int nbuck, const int* __restrict__ S, int* __restrict__ tmp) {
  extern __shared__ int cur1[];
  const int t = threadIdx.x;
  for (int k = t; k < nbuck; k += 256) cur1[k] = S[k * 256 + blockIdx.x];
  __syncthreads();
  const int chunk = (E + 255) / 256;
  const int s = blockIdx.x * chunk;
  const int e = min(E, s + chunk);
  for (int i = s + t; i < e; i += 256) {
    const int sv = src[i];
    const int d = dst[i];
    const int pos1 = atomicAdd(&cur1[d >> 8], 1);
    tmp[pos1] = sv | ((d & 255) << 20);
  }
}

// passD: per bucket: dst-side hist + scan -> rowStart, nd, edgeSrc; ns from degout.
__global__ void k_passD(const int* __restrict__ tmp, const int* __restrict__ S,
                        int nbuck, int N, int E,
                        int* __restrict__ rowStart, int* __restrict__ edgeSrc,
                        const int* __restrict__ degout,
                        float* __restrict__ ns, float* __restrict__ nd) {
  __shared__ int h[256];
  __shared__ int ex[256];
  __shared__ int c[256];
  const int t = threadIdx.x;
  const int k = blockIdx.x;
  const int node = k * 256 + t;
  const int bs = S[k * 256];
  const int be = (k + 1 < nbuck) ? S[(k + 1) * 256] : E;
  h[t] = 0;
  __syncthreads();
  for (int i = bs + t; i < be; i += 256) atomicAdd(&h[tmp[i] >> 20], 1);
  __syncthreads();
  const int cnt = h[t];
  ex[t] = cnt;
  __syncthreads();
  for (int off = 1; off < 256; off <<= 1) {
    int u = (t >= off) ? ex[t - off] : 0;
    __syncthreads();
    ex[t] += u;
    __syncthreads();
  }
  const int excl = ex[t] - cnt;
  if (node < N) {
    rowStart[node] = bs + excl;
    nd[node] = rsqrtf((float)(cnt > 0 ? cnt : 1));
    int dov = degout[node];
    if (dov <= 0) dov = 1;
    ns[node] = rsqrtf((float)dov);
  }
  c[t] = bs + excl;
  __syncthreads();
  for (int i = bs + t; i < be; i += 256) {
    const int v = tmp[i];
    const int pos = atomicAdd(&c[v >> 20], 1);
    edgeSrc[pos] = v & 0xFFFFF;
  }
}

// ---------------- MFMA GEMM (LDS-staged W + A-prefetch + vectorized C) ---------------
// Round-3 proven structure (W staged once/block into LDS transposed [n][K], B-frag =
// one contiguous ds_read_b128; C transposed through per-wave LDS -> 16B stores),
// plus: balanced grid (every wave exactly 2 groups) and cross-group A-prefetch.
template <int K, bool FIRST, bool SCALE>
__device__ __forceinline__ void gemm_loadA(const void* hin, bool isb, int rowA,
                                           int quad, bf16x8* A) {
  constexpr int KT = K / 32;
  if (FIRST && !isb) {
    const float* hp = (const float*)hin + (size_t)rowA * K;
#pragma unroll
    for (int kt = 0; kt < KT; ++kt) {
      const float4 u0 = *(const float4*)(hp + kt * 32 + quad * 8);
      const float4 u1 = *(const float4*)(hp + kt * 32 + quad * 8 + 4);
      A[kt][0] = (short)f2b(u0.x); A[kt][1] = (short)f2b(u0.y);
      A[kt][2] = (short)f2b(u0.z); A[kt][3] = (short)f2b(u0.w);
      A[kt][4] = (short)f2b(u1.x); A[kt][5] = (short)f2b(u1.y);
      A[kt][6] = (short)f2b(u1.z); A[kt][7] = (short)f2b(u1.w);
    }
  } else {
    const unsigned short* hp = (const unsigned short*)hin + (size_t)rowA * K;
#pragma unroll
    for (int kt = 0; kt < KT; ++kt)
      A[kt] = *(const bf16x8*)(hp + kt * 32 + quad * 8);
  }
}

template <int K, bool FIRST, bool SCALE>
__global__ void __launch_bounds__(256) k_gemm(
    const void* __restrict__ hin, const void* __restrict__ Wv,
    const int* __restrict__ flag, const float* __restrict__ norm_src,
    int N, unsigned short* __restrict__ out) {
  constexpr int KT = K / 32;
  constexpr int ST = K + 8;     // W-tile row stride (shorts)
  constexpr int CST = 72;       // C-tile row stride (shorts)
  __shared__ unsigned short Wl[64 * ST];
  __shared__ unsigned short Cl[4][16 * CST];
  const bool isb = (*flag != 0);
  const int tid = threadIdx.x;

  // ---- stage W once per block: W[k][n] -> Wl[n][k] (bf16) ----
  {
    const unsigned short* Wus = (const unsigned short*)Wv;
    const float* Wf = (const float*)Wv;
    for (int i0 = tid * 8; i0 < K * 64; i0 += 2048) {
      const int k = i0 >> 6;
      const int n0 = i0 & 63;
      unsigned short v[8];
      if (isb) {
        const u16x8 u = *(const u16x8*)(Wus + i0);
#pragma unroll
        for (int j = 0; j < 8; ++j) v[j] = u[j];
      } else {
        const float4 f0 = *(const float4*)(Wf + i0);
        const float4 f1 = *(const float4*)(Wf + i0 + 4);
        v[0] = f2b(f0.x); v[1] = f2b(f0.y); v[2] = f2b(f0.z); v[3] = f2b(f0.w);
        v[4] = f2b(f1.x); v[5] = f2b(f1.y); v[6] = f2b(f1.z); v[7] = f2b(f1.w);
      }
#pragma unroll
      for (int j = 0; j < 8; ++j) Wl[(n0 + j) * ST + k] = v[j];
    }
  }
  __syncthreads();

  const int lane = tid & 63;
  const int quad = lane >> 4;
  const int l16 = lane & 15;
  const int w = tid >> 6;
  unsigned short* myC = &Cl[w][0];

  const int wid = blockIdx.x * 4 + w;
  const int nw = gridDim.x * 4;
  const int G = (N + 15) >> 4;

  bf16x8 A0[KT], A1[KT];
  if (wid < G) {
    int r0 = (wid << 4) + l16;
    if (r0 >= N) r0 = N - 1;
    gemm_loadA<K, FIRST, SCALE>(hin, isb, r0, quad, A0);
  }
  for (int g = wid; g < G; g += nw) {
    if (g + nw < G) {
      int r1 = ((g + nw) << 4) + l16;
      if (r1 >= N) r1 = N - 1;
      gemm_loadA<K, FIRST, SCALE>(hin, isb, r1, quad, A1);
    }
    f32x4 acc[4] = {{0.f, 0.f, 0.f, 0.f}, {0.f, 0.f, 0.f, 0.f},
                    {0.f, 0.f, 0.f, 0.f}, {0.f, 0.f, 0.f, 0.f}};
#pragma unroll
    for (int kt = 0; kt < KT; ++kt) {
      const int koff = kt * 32 + quad * 8;
#pragma unroll
      for (int nt = 0; nt < 4; ++nt) {
        const bf16x8 Bf = *(const bf16x8*)&Wl[(nt * 16 + l16) * ST + koff];
        acc[nt] = __builtin_amdgcn_mfma_f32_16x16x32_bf16(A0[kt], Bf, acc[nt], 0, 0, 0);
      }
    }
    // epilogue: acc -> per-wave LDS tile (transpose) -> coalesced 16B stores
    const int rowD = quad * 4;
#pragma unroll
    for (int r = 0; r < 4; ++r) {
      const int nodeW = (g << 4) + rowD + r;
      const float f = (SCALE && nodeW < N) ? norm_src[nodeW] : 1.0f;
#pragma unroll
      for (int nt = 0; nt < 4; ++nt)
        myC[(rowD + r) * CST + nt * 16 + l16] = f2b(SCALE ? acc[nt][r] * f : acc[nt][r]);
    }
    const int row2 = lane >> 2;
    const int c0 = (lane & 3) * 16;
    const int node = (g << 4) + row2;
    if (node < N) {
      const u16x8 v0 = *(const u16x8*)&myC[row2 * CST + c0];
      const u16x8 v1 = *(const u16x8*)&myC[row2 * CST + c0 + 8];
      *(u16x8*)(out + (size_t)node * 64 + c0) = v0;
      *(u16x8*)(out + (size_t)node * 64 + c0 + 8) = v1;
    }
#pragma unroll
    for (int kt = 0; kt < KT; ++kt) A0[kt] = A1[kt];
  }
}

// ---------------- MFMA aggregation (SpMM with segment-indicator A) -------------------
__device__ __forceinline__ void agg_chunk_compute(unsigned trbase, int cb32, int lo,
                                                  unsigned span, int quad, f32x4* acc) {
  const int posbase = cb32 + (quad << 2);
  const unsigned u0 = (unsigned)(posbase - lo);
  bf16x8 Af;
#pragma unroll
  for (int j = 0; j < 8; ++j) {
    const unsigned off = (j < 4) ? (unsigned)j : (unsigned)(12 + j);
    Af[j] = ((u0 + off) < span) ? (short)0x3F80 : (short)0;
  }
  s16x4 t0[4], t1[4];
#pragma unroll
  for (int nt = 0; nt < 4; ++nt) {
    const unsigned a = trbase + (unsigned)(nt * 1024);
    asm volatile("ds_read_b64_tr_b16 %0, %1" : "=v"(t0[nt]) : "v"(a) : "memory");
    asm volatile("ds_read_b64_tr_b16 %0, %1 offset:512" : "=v"(t1[nt]) : "v"(a) : "memory");
  }
  asm volatile("s_waitcnt lgkmcnt(0)" ::: "memory");
  __builtin_amdgcn_sched_barrier(0);
#pragma unroll
  for (int nt = 0; nt < 4; ++nt) {
    bf16x8 Bf;
    Bf[0] = t0[nt][0]; Bf[1] = t0[nt][1]; Bf[2] = t0[nt][2]; Bf[3] = t0[nt][3];
    Bf[4] = t1[nt][0]; Bf[5] = t1[nt][1]; Bf[6] = t1[nt][2]; Bf[7] = t1[nt][3];
    acc[nt] = __builtin_amdgcn_mfma_f32_16x16x32_bf16(Af, Bf, acc[nt], 0, 0, 0);
  }
}

template <bool LAST>
__global__ void __launch_bounds__(256) k_aggregate(
    const unsigned short* __restrict__ proj,
    const int* __restrict__ edgeSrc, const int* __restrict__ rowStart,
    const float* __restrict__ norm_dst, const float* __restrict__ norm_src,
    const void* __restrict__ bias, const int* __restrict__ flag,
    int N, int E, void* __restrict__ outp) {
  __shared__ unsigned short lds[4][2048];  // 4 KB per wave: [32 edges][64 cols]
  const bool isb = (*flag != 0);
  const int tid = threadIdx.x;
  const int w = tid >> 6;
  const int lane = tid & 63;
  const int l16 = lane & 15;
  const int quad = lane >> 4;
  const int e32 = lane & 31;  // edge slot within chunk
  const int p = lane >> 5;    // 64-byte half of the 128-byte row

  const int wid = blockIdx.x * 4 + w;
  const int g0 = wid * 8;

  float bcol[4];
#pragma unroll
  for (int nt = 0; nt < 4; ++nt) {
    const int col = nt * 16 + l16;
    bcol[nt] = isb ? b2f(((const unsigned short*)bias)[col]) : ((const float*)bias)[col];
  }

  const int cb = rowStart[min(g0, N)];
  const int ce = rowStart[min(g0 + 8, N)];
  const int L = ce - cb;
  const int nch = (L + 31) >> 5;

  const int rsi = min(g0 + min(l16, 8), N);
  const int rsj = min(g0 + min(l16 + 1, 8), N);
  const int lo = rowStart[rsi];
  const unsigned span = (unsigned)(rowStart[rsj] - lo);

  int idxc[6];
#pragma unroll
  for (int t = 0; t < 6; ++t) {
    const int pos = min(cb + t * 32 + e32, E - 1);
    idxc[t] = edgeSrc[pos];
  }

  unsigned short* myl = &lds[w][0];
  unsigned wofs[4];
#pragma unroll
  for (int q = 0; q < 4; ++q) {
    const int n0 = p * 32 + q * 8;
    wofs[q] = (unsigned)((n0 >> 4) * 512 + e32 * 16 + (n0 & 15));
  }
  const unsigned trbase = (unsigned)(uintptr_t)myl + (unsigned)lane * 8u;

  f32x4 acc[4] = {{0.f, 0.f, 0.f, 0.f}, {0.f, 0.f, 0.f, 0.f},
                  {0.f, 0.f, 0.f, 0.f}, {0.f, 0.f, 0.f, 0.f}};

  i32x4 gb[2][4];
#define AGG_ISSUE(t, b)                                                         \
  {                                                                             \
    const unsigned short* rp = proj + (size_t)idxc[t] * 64 + p * 32;            \
    gb[b][0] = *(const i32x4*)(rp);                                             \
    gb[b][1] = *(const i32x4*)(rp + 8);                                         \
    gb[b][2] = *(const i32x4*)(rp + 16);                                        \
    gb[b][3] = *(const i32x4*)(rp + 24);                                        \
  }
  if (0 < nch) AGG_ISSUE(0, 0);
  if (1 < nch) AGG_ISSUE(1, 1);

#pragma unroll
  for (int tt = 0; tt < 6; ++tt) {
    if (tt < nch) {
#pragma unroll
      for (int q = 0; q < 4; ++q) *(i32x4*)(myl + wofs[q]) = gb[tt & 1][q];
      if (tt + 2 < 6 && tt + 2 < nch) AGG_ISSUE(tt + 2, tt & 1);
      asm volatile("s_waitcnt lgkmcnt(0)" ::: "memory");
      agg_chunk_compute(trbase, cb + tt * 32, lo, span, quad, acc);
    }
  }
  for (int t = 6; t < nch; ++t) {
    const int pos = min(cb + t * 32 + e32, E - 1);
    const int idx = edgeSrc[pos];
    const unsigned short* rp = proj + (size_t)idx * 64 + p * 32;
    i32x4 g4[4];
    g4[0] = *(const i32x4*)(rp);
    g4[1] = *(const i32x4*)(rp + 8);
    g4[2] = *(const i32x4*)(rp + 16);
    g4[3] = *(const i32x4*)(rp + 24);
#pragma unroll
    for (int q = 0; q < 4; ++q) *(i32x4*)(myl + wofs[q]) = g4[q];
    asm volatile("s_waitcnt lgkmcnt(0)" ::: "memory");
    agg_chunk_compute(trbase, cb + t * 32, lo, span, quad, acc);
  }
#undef AGG_ISSUE

  // ---- epilogue: finalize -> stage[w] -> coalesced stores (kills 2B-store RMW) ----
  if (LAST && !isb) {
    float* fs = (float*)myl;
#pragma unroll
    for (int reg = 0; reg < 4; ++reg) {
      const int row = quad * 4 + reg;
      if (row < 8) {
        const int node = min(g0 + row, N - 1);
        const float nd = norm_dst[node];
#pragma unroll
        for (int nt = 0; nt < 4; ++nt)
          fs[row * 64 + nt * 16 + l16] = fmaxf(fmaf(acc[nt][reg], nd, bcol[nt]), 0.f);
      }
    }
    asm volatile("s_waitcnt lgkmcnt(0)" ::: "memory");
    __builtin_amdgcn_sched_barrier(0);
    const int r = lane >> 3;
    const int c0 = (lane & 7) * 8;
    const int node = g0 + r;
    if (node < N) {
      const float4 v0 = *(const float4*)&fs[r * 64 + c0];
      const float4 v1 = *(const float4*)&fs[r * 64 + c0 + 4];
      float* of = (float*)outp + (size_t)node * 64 + c0;
      *(float4*)of = v0;
      *(float4*)(of + 4) = v1;
    }
  } else {
#pragma unroll
    for (int reg = 0; reg < 4; ++reg) {
      const int row = quad * 4 + reg;
      if (row < 8) {
        const int node = min(g0 + row, N - 1);
        const float nd = norm_dst[node];
        const float esc = LAST ? 1.f : norm_src[node];
#pragma unroll
        for (int nt = 0; nt < 4; ++nt) {
          float x = fmaxf(fmaf(acc[nt][reg], nd, bcol[nt]), 0.f);
          if (!LAST) x *= esc;
          myl[row * 64 + nt * 16 + l16] = f2b(x);
        }
      }
    }
    asm volatile("s_waitcnt lgkmcnt(0)" ::: "memory");
    __builtin_amdgcn_sched_barrier(0);
    if (lane < 32) {
      const int r = lane >> 2;
      const int c0 = (lane & 3) * 16;
      const int node = g0 + r;
      if (node < N) {
        const u16x8 v0 = *(const u16x8*)&myl[r * 64 + c0];
        const u16x8 v1 = *(const u16x8*)&myl[r * 64 + c0 + 8];
        *(u16x8*)((unsigned short*)outp + (size_t)node * 64 + c0) = v0;
        *(u16x8*)((unsigned short*)outp + (size_t)node * 64 + c0 + 8) = v1;
      }
    }
  }
}

extern "C" void kernel_launch(void* const* d_in, const int* in_sizes, int n_in,
                              void* d_out, int out_size, void* d_ws, size_t ws_size,
                              hipStream_t stream) {
  const void* features = d_in[0];
  const void* W0 = d_in[1];
  const void* b0 = d_in[2];
  const void* W1 = d_in[3];
  const void* b1 = d_in[4];
  const void* W2 = d_in[5];
  const void* b2 = d_in[6];
  const int* src = (const int*)d_in[7];
  const int* dst = (const int*)d_in[8];
  const int N = in_sizes[0] / 128;
  const int E = in_sizes[7];
  const int NBUCK = (N + 255) >> 8;
  const int M = NBUCK * 256;

  char* w = (char*)d_ws;
  size_t off = 0;
  auto alloc = [&](size_t bytes) {
    void* p = w + off;
    off = (off + bytes + 255) & ~(size_t)255;
    return p;
  };
  int* flag = (int*)alloc(4);
  int* rowStart = (int*)alloc((size_t)(N + 1) * 4);
  int* counts = (int*)alloc((size_t)M * 4);
  int* bsums = (int*)alloc(1024 * 4);
  float* norm_src = (float*)alloc((size_t)N * 4);
  float* norm_dst = (float*)alloc((size_t)N * 4);
  int* degout = (int*)alloc((size_t)N * 4);
  int* tmp = (int*)alloc((size_t)E * 4);
  int* edgeSrc = (int*)alloc((size_t)E * 4);
  unsigned short* projA = (unsigned short*)alloc((size_t)N * 64 * 2);  // bf16
  unsigned short* hB = (unsigned short*)d_out;  // inter-layer h (bf16) in d_out

  const size_t lds_nb = (size_t)NBUCK * 4;  // single dst hist/cursor array
  const int G16 = (N + 15) / 16;            // 16-row groups
  const int GB = (G16 + 7) / 8;             // exactly 2 groups per wave, balanced

  // CSR build.
  hipMemsetAsync(degout, 0, (size_t)N * 4, stream);
  k_passA<<<257, 256, lds_nb, stream>>>(src, dst, E, NBUCK, counts,
                                        (const unsigned short*)features, flag, degout);
  k_scan1<<<NBUCK, 256, 0, stream>>>(counts, M, bsums);
  k_scan2<<<1, 1024, 0, stream>>>(bsums, NBUCK, rowStart, N, E);
  k_scan3<<<NBUCK, 256, 0, stream>>>(counts, M, bsums);
  k_passC<<<256, 256, lds_nb, stream>>>(src, dst, E, NBUCK, counts, tmp);
  k_passD<<<NBUCK, 256, 0, stream>>>(tmp, counts, NBUCK, N, E,
                                     rowStart, edgeSrc, degout, norm_src, norm_dst);

  const int AB = (((N + 7) / 8) + 3) / 4;  // 8 nodes/wave, 4 waves/block
  // layer 0 (ns folded into gemm0 epilogue)
  k_gemm<128, true, true><<<GB, 256, 0, stream>>>(features, W0, flag, norm_src, N, projA);
  k_aggregate<false><<<AB, 256, 0, stream>>>(projA, edgeSrc, rowStart, norm_dst, norm_src, b0, flag, N, E, hB);
  // layer 1 (h pre-scaled by ns in agg epilogue)
  k_gemm<64, false, false><<<GB, 256, 0, stream>>>(hB, W1, flag, nullptr, N, projA);
  k_aggregate<false><<<AB, 256, 0, stream>>>(projA, edgeSrc, rowStart, norm_dst, norm_src, b1, flag, N, E, hB);
  // layer 2 -> d_out
  k_gemm<64, false, false><<<GB, 256, 0, stream>>>(hB, W2, flag, nullptr, N, projA);
  k_aggregate<true><<<AB, 256, 0, stream>>>(projA, edgeSrc, rowStart, norm_dst, norm_src, b2, flag, N, E, d_out);
}

// Round 6
// 315.439 us; speedup vs baseline: 1.1331x; 1.1331x over previous
//
#include <hip/hip_runtime.h>
#include <hip/hip_bf16.h>

typedef __hip_bfloat16 bf16;
typedef __attribute__((ext_vector_type(8))) short bf16x8;
typedef __attribute__((ext_vector_type(8))) unsigned short u16x8;
typedef __attribute__((ext_vector_type(4))) float f32x4;
typedef __attribute__((ext_vector_type(4))) int i32x4;
typedef __attribute__((ext_vector_type(4))) short s16x4;

__device__ __forceinline__ float b2f(unsigned short u) {
  return __uint_as_float(((unsigned)u) << 16);
}
__device__ __forceinline__ unsigned short f2b(float x) {
  bf16 h = __float2bfloat16(x);
  return *reinterpret_cast<unsigned short*>(&h);
}

// ============== passA: coarse hist of dst AND src + dtype probe ==============
// counts[0..M): dst buckets (counts[k*256+b]); counts[M..2M): src buckets.
__global__ void k_passA(const int* __restrict__ src, const int* __restrict__ dst, int E,
                        int nbuck, int M, int* __restrict__ counts,
                        const unsigned short* __restrict__ raw, int* __restrict__ flag) {
  if (blockIdx.x == 256) {
    __shared__ int sbad, snz;
    const int t = threadIdx.x;
    if (t == 0) { sbad = 0; snz = 0; }
    __syncthreads();
    const unsigned short u = raw[t];
    const float a = fabsf(b2f(u));
    if (!(a < 100.f)) atomicAdd(&sbad, 1);
    if (((t & 1) == 0) && u != 0) atomicAdd(&snz, 1);
    __syncthreads();
    if (t == 0) flag[0] = (sbad == 0 && snz > 0) ? 1 : 0;
    return;
  }
  extern __shared__ int lh[];  // lh1[nbuck] then lh2[nbuck]
  int* lh1 = lh;
  int* lh2 = lh + nbuck;
  const int t = threadIdx.x;
  for (int k = t; k < 2 * nbuck; k += 256) lh[k] = 0;
  __syncthreads();
  const int chunk = (E + 255) / 256;
  const int s = blockIdx.x * chunk;
  const int e = min(E, s + chunk);
  for (int i = s + t; i < e; i += 256) {
    atomicAdd(&lh1[dst[i] >> 8], 1);
    atomicAdd(&lh2[src[i] >> 8], 1);
  }
  __syncthreads();
  for (int k = t; k < nbuck; k += 256) {
    counts[k * 256 + blockIdx.x] = lh1[k];
    counts[M + k * 256 + blockIdx.x] = lh2[k];
  }
}

// exclusive scan over 2M ints
__global__ void k_scan1(const int* __restrict__ a, int M2, int* __restrict__ bsums) {
  __shared__ int sdata[256];
  int i = blockIdx.x * 256 + threadIdx.x;
  int v = (i < M2) ? a[i] : 0;
  sdata[threadIdx.x] = v;
  __syncthreads();
  for (int s = 128; s > 0; s >>= 1) {
    if (threadIdx.x < s) sdata[threadIdx.x] += sdata[threadIdx.x + s];
    __syncthreads();
  }
  if (threadIdx.x == 0) bsums[blockIdx.x] = sdata[0];
}

__global__ void k_scan2(int* __restrict__ bsums, int nb, int* __restrict__ rowStart,
                        int N, int E) {
  __shared__ int s[1024];
  const int t = threadIdx.x;
  const int v = (t < nb) ? bsums[t] : 0;
  s[t] = v;
  __syncthreads();
  for (int off = 1; off < 1024; off <<= 1) {
    int u = (t >= off) ? s[t - off] : 0;
    __syncthreads();
    s[t] += u;
    __syncthreads();
  }
  if (t < nb) bsums[t] = s[t] - v;  // exclusive
  if (t == 0) rowStart[N] = E;
}

__global__ void k_scan3(int* __restrict__ a, int M2, const int* __restrict__ bsums) {
  __shared__ int sdata[256];
  int i = blockIdx.x * 256 + threadIdx.x;
  int v = (i < M2) ? a[i] : 0;
  sdata[threadIdx.x] = v;
  __syncthreads();
  for (int off = 1; off < 256; off <<= 1) {
    int t = (threadIdx.x >= off) ? sdata[threadIdx.x - off] : 0;
    __syncthreads();
    sdata[threadIdx.x] += t;
    __syncthreads();
  }
  if (i < M2) a[i] = bsums[blockIdx.x] + sdata[threadIdx.x] - v;  // exclusive
}

// passC: dual scatter via LDS cursors — ZERO global atomics.
__global__ void k_passC(const int* __restrict__ src, const int* __restrict__ dst, int E,
                        int nbuck, int M, const int* __restrict__ S,
                        int* __restrict__ tmp, unsigned char* __restrict__ tmp2) {
  extern __shared__ int cur[];  // cur1[nbuck], cur2[nbuck]
  int* cur1 = cur;
  int* cur2 = cur + nbuck;
  const int t = threadIdx.x;
  for (int k = t; k < nbuck; k += 256) {
    cur1[k] = S[k * 256 + blockIdx.x];
    cur2[k] = S[M + k * 256 + blockIdx.x];
  }
  __syncthreads();
  const int chunk = (E + 255) / 256;
  const int s = blockIdx.x * chunk;
  const int e = min(E, s + chunk);
  for (int i = s + t; i < e; i += 256) {
    const int sv = src[i];
    const int d = dst[i];
    const int pos1 = atomicAdd(&cur1[d >> 8], 1);
    tmp[pos1] = sv | ((d & 255) << 20);
    const int pos2 = atomicAdd(&cur2[sv >> 8], 1);
    tmp2[pos2 - E] = (unsigned char)(sv & 255);
  }
}

// passD: per bucket k: (1) src-side byte hist -> deg_out -> ns;
//        (2) dst-side hist + scan -> rowStart, nd, edgeSrc scatter.
__global__ void k_passD(const int* __restrict__ tmp, const unsigned char* __restrict__ tmp2,
                        const int* __restrict__ S, int nbuck, int M, int N, int E,
                        int* __restrict__ rowStart, int* __restrict__ edgeSrc,
                        float* __restrict__ ns, float* __restrict__ nd) {
  __shared__ int h[256];
  __shared__ int ex[256];
  __shared__ int c[256];
  const int t = threadIdx.x;
  const int k = blockIdx.x;
  const int node = k * 256 + t;
  // ---- phase 1: src-side (deg_out -> ns) ----
  const int bs2 = S[M + k * 256] - E;
  const int be2 = (k + 1 < nbuck) ? (S[M + (k + 1) * 256] - E) : E;
  h[t] = 0;
  __syncthreads();
  for (int i = bs2 + t; i < be2; i += 256) atomicAdd(&h[tmp2[i]], 1);
  __syncthreads();
  if (node < N) {
    int dov = h[t];
    if (dov <= 0) dov = 1;
    ns[node] = rsqrtf((float)dov);
  }
  __syncthreads();
  // ---- phase 2: dst-side (rowStart, nd, edgeSrc) ----
  const int bs = S[k * 256];
  const int be = (k + 1 < nbuck) ? S[(k + 1) * 256] : E;
  h[t] = 0;
  __syncthreads();
  for (int i = bs + t; i < be; i += 256) atomicAdd(&h[tmp[i] >> 20], 1);
  __syncthreads();
  const int cnt = h[t];
  ex[t] = cnt;
  __syncthreads();
  for (int off = 1; off < 256; off <<= 1) {
    int u = (t >= off) ? ex[t - off] : 0;
    __syncthreads();
    ex[t] += u;
    __syncthreads();
  }
  const int excl = ex[t] - cnt;
  if (node < N) {
    rowStart[node] = bs + excl;
    nd[node] = rsqrtf((float)(cnt > 0 ? cnt : 1));
  }
  c[t] = bs + excl;
  __syncthreads();
  for (int i = bs + t; i < be; i += 256) {
    const int v = tmp[i];
    const int pos = atomicAdd(&c[v >> 20], 1);
    edgeSrc[pos] = v & 0xFFFFF;
  }
}

// ---------------- MFMA GEMM (LDS-staged W + A-prefetch + vectorized C) ---------------
template <int K, bool FIRST, bool SCALE>
__device__ __forceinline__ void gemm_loadA(const void* hin, bool isb, int rowA,
                                           int quad, bf16x8* A) {
  constexpr int KT = K / 32;
  if (FIRST && !isb) {
    const float* hp = (const float*)hin + (size_t)rowA * K;
#pragma unroll
    for (int kt = 0; kt < KT; ++kt) {
      const float4 u0 = *(const float4*)(hp + kt * 32 + quad * 8);
      const float4 u1 = *(const float4*)(hp + kt * 32 + quad * 8 + 4);
      A[kt][0] = (short)f2b(u0.x); A[kt][1] = (short)f2b(u0.y);
      A[kt][2] = (short)f2b(u0.z); A[kt][3] = (short)f2b(u0.w);
      A[kt][4] = (short)f2b(u1.x); A[kt][5] = (short)f2b(u1.y);
      A[kt][6] = (short)f2b(u1.z); A[kt][7] = (short)f2b(u1.w);
    }
  } else {
    const unsigned short* hp = (const unsigned short*)hin + (size_t)rowA * K;
#pragma unroll
    for (int kt = 0; kt < KT; ++kt)
      A[kt] = *(const bf16x8*)(hp + kt * 32 + quad * 8);
  }
}

template <int K, bool FIRST, bool SCALE>
__global__ void __launch_bounds__(256) k_gemm(
    const void* __restrict__ hin, const void* __restrict__ Wv,
    const int* __restrict__ flag, const float* __restrict__ norm_src,
    int N, unsigned short* __restrict__ out) {
  constexpr int KT = K / 32;
  constexpr int ST = K + 8;     // W-tile row stride (shorts)
  constexpr int CST = 72;       // C-tile row stride (shorts)
  __shared__ unsigned short Wl[64 * ST];
  __shared__ unsigned short Cl[4][16 * CST];
  const bool isb = (*flag != 0);
  const int tid = threadIdx.x;

  // ---- stage W once per block: W[k][n] -> Wl[n][k] (bf16) ----
  {
    const unsigned short* Wus = (const unsigned short*)Wv;
    const float* Wf = (const float*)Wv;
    for (int i0 = tid * 8; i0 < K * 64; i0 += 2048) {
      const int k = i0 >> 6;
      const int n0 = i0 & 63;
      unsigned short v[8];
      if (isb) {
        const u16x8 u = *(const u16x8*)(Wus + i0);
#pragma unroll
        for (int j = 0; j < 8; ++j) v[j] = u[j];
      } else {
        const float4 f0 = *(const float4*)(Wf + i0);
        const float4 f1 = *(const float4*)(Wf + i0 + 4);
        v[0] = f2b(f0.x); v[1] = f2b(f0.y); v[2] = f2b(f0.z); v[3] = f2b(f0.w);
        v[4] = f2b(f1.x); v[5] = f2b(f1.y); v[6] = f2b(f1.z); v[7] = f2b(f1.w);
      }
#pragma unroll
      for (int j = 0; j < 8; ++j) Wl[(n0 + j) * ST + k] = v[j];
    }
  }
  __syncthreads();

  const int lane = tid & 63;
  const int quad = lane >> 4;
  const int l16 = lane & 15;
  const int w = tid >> 6;
  unsigned short* myC = &Cl[w][0];

  const int wid = blockIdx.x * 4 + w;
  const int nw = gridDim.x * 4;
  const int G = (N + 15) >> 4;

  bf16x8 A0[KT], A1[KT];
  if (wid < G) {
    int r0 = (wid << 4) + l16;
    if (r0 >= N) r0 = N - 1;
    gemm_loadA<K, FIRST, SCALE>(hin, isb, r0, quad, A0);
  }
  for (int g = wid; g < G; g += nw) {
    if (g + nw < G) {
      int r1 = ((g + nw) << 4) + l16;
      if (r1 >= N) r1 = N - 1;
      gemm_loadA<K, FIRST, SCALE>(hin, isb, r1, quad, A1);
    }
    f32x4 acc[4] = {{0.f, 0.f, 0.f, 0.f}, {0.f, 0.f, 0.f, 0.f},
                    {0.f, 0.f, 0.f, 0.f}, {0.f, 0.f, 0.f, 0.f}};
#pragma unroll
    for (int kt = 0; kt < KT; ++kt) {
      const int koff = kt * 32 + quad * 8;
#pragma unroll
      for (int nt = 0; nt < 4; ++nt) {
        const bf16x8 Bf = *(const bf16x8*)&Wl[(nt * 16 + l16) * ST + koff];
        acc[nt] = __builtin_amdgcn_mfma_f32_16x16x32_bf16(A0[kt], Bf, acc[nt], 0, 0, 0);
      }
    }
    // epilogue: acc -> per-wave LDS tile (transpose) -> coalesced 16B stores
    const int rowD = quad * 4;
#pragma unroll
    for (int r = 0; r < 4; ++r) {
      const int nodeW = (g << 4) + rowD + r;
      const float f = (SCALE && nodeW < N) ? norm_src[nodeW] : 1.0f;
#pragma unroll
      for (int nt = 0; nt < 4; ++nt)
        myC[(rowD + r) * CST + nt * 16 + l16] = f2b(SCALE ? acc[nt][r] * f : acc[nt][r]);
    }
    const int row2 = lane >> 2;
    const int c0 = (lane & 3) * 16;
    const int node = (g << 4) + row2;
    if (node < N) {
      const u16x8 v0 = *(const u16x8*)&myC[row2 * CST + c0];
      const u16x8 v1 = *(const u16x8*)&myC[row2 * CST + c0 + 8];
      *(u16x8*)(out + (size_t)node * 64 + c0) = v0;
      *(u16x8*)(out + (size_t)node * 64 + c0 + 8) = v1;
    }
#pragma unroll
    for (int kt = 0; kt < KT; ++kt) A0[kt] = A1[kt];
  }
}

// ---------------- MFMA aggregation (SpMM with segment-indicator A) -------------------
__device__ __forceinline__ void agg_chunk_compute(unsigned trbase, int cb32, int lo,
                                                  unsigned span, int quad, f32x4* acc) {
  const int posbase = cb32 + (quad << 2);
  const unsigned u0 = (unsigned)(posbase - lo);
  bf16x8 Af;
#pragma unroll
  for (int j = 0; j < 8; ++j) {
    const unsigned off = (j < 4) ? (unsigned)j : (unsigned)(12 + j);
    Af[j] = ((u0 + off) < span) ? (short)0x3F80 : (short)0;
  }
  s16x4 t0[4], t1[4];
#pragma unroll
  for (int nt = 0; nt < 4; ++nt) {
    const unsigned a = trbase + (unsigned)(nt * 1024);
    asm volatile("ds_read_b64_tr_b16 %0, %1" : "=v"(t0[nt]) : "v"(a) : "memory");
    asm volatile("ds_read_b64_tr_b16 %0, %1 offset:512" : "=v"(t1[nt]) : "v"(a) : "memory");
  }
  asm volatile("s_waitcnt lgkmcnt(0)" ::: "memory");
  __builtin_amdgcn_sched_barrier(0);
#pragma unroll
  for (int nt = 0; nt < 4; ++nt) {
    bf16x8 Bf;
    Bf[0] = t0[nt][0]; Bf[1] = t0[nt][1]; Bf[2] = t0[nt][2]; Bf[3] = t0[nt][3];
    Bf[4] = t1[nt][0]; Bf[5] = t1[nt][1]; Bf[6] = t1[nt][2]; Bf[7] = t1[nt][3];
    acc[nt] = __builtin_amdgcn_mfma_f32_16x16x32_bf16(Af, Bf, acc[nt], 0, 0, 0);
  }
}

template <bool LAST>
__global__ void __launch_bounds__(256) k_aggregate(
    const unsigned short* __restrict__ proj,
    const int* __restrict__ edgeSrc, const int* __restrict__ rowStart,
    const float* __restrict__ norm_dst, const float* __restrict__ norm_src,
    const void* __restrict__ bias, const int* __restrict__ flag,
    int N, int E, void* __restrict__ outp) {
  __shared__ unsigned short lds[4][2048];  // 4 KB per wave: [32 edges][64 cols]
  const bool isb = (*flag != 0);
  const int tid = threadIdx.x;
  const int w = tid >> 6;
  const int lane = tid & 63;
  const int l16 = lane & 15;
  const int quad = lane >> 4;
  const int e32 = lane & 31;  // edge slot within chunk
  const int p = lane >> 5;    // 64-byte half of the 128-byte row

  const int wid = blockIdx.x * 4 + w;
  const int g0 = wid * 8;

  float bcol[4];
#pragma unroll
  for (int nt = 0; nt < 4; ++nt) {
    const int col = nt * 16 + l16;
    bcol[nt] = isb ? b2f(((const unsigned short*)bias)[col]) : ((const float*)bias)[col];
  }

  const int cb = rowStart[min(g0, N)];
  const int ce = rowStart[min(g0 + 8, N)];
  const int L = ce - cb;
  const int nch = (L + 31) >> 5;

  const int rsi = min(g0 + min(l16, 8), N);
  const int rsj = min(g0 + min(l16 + 1, 8), N);
  const int lo = rowStart[rsi];
  const unsigned span = (unsigned)(rowStart[rsj] - lo);

  int idxc[6];
#pragma unroll
  for (int t = 0; t < 6; ++t) {
    const int pos = min(cb + t * 32 + e32, E - 1);
    idxc[t] = edgeSrc[pos];
  }

  unsigned short* myl = &lds[w][0];
  unsigned wofs[4];
#pragma unroll
  for (int q = 0; q < 4; ++q) {
    const int n0 = p * 32 + q * 8;
    wofs[q] = (unsigned)((n0 >> 4) * 512 + e32 * 16 + (n0 & 15));
  }
  const unsigned trbase = (unsigned)(uintptr_t)myl + (unsigned)lane * 8u;

  f32x4 acc[4] = {{0.f, 0.f, 0.f, 0.f}, {0.f, 0.f, 0.f, 0.f},
                  {0.f, 0.f, 0.f, 0.f}, {0.f, 0.f, 0.f, 0.f}};

  i32x4 gb[2][4];
#define AGG_ISSUE(t, b)                                                         \
  {                                                                             \
    const unsigned short* rp = proj + (size_t)idxc[t] * 64 + p * 32;            \
    gb[b][0] = *(const i32x4*)(rp);                                             \
    gb[b][1] = *(const i32x4*)(rp + 8);                                         \
    gb[b][2] = *(const i32x4*)(rp + 16);                                        \
    gb[b][3] = *(const i32x4*)(rp + 24);                                        \
  }
  if (0 < nch) AGG_ISSUE(0, 0);
  if (1 < nch) AGG_ISSUE(1, 1);

#pragma unroll
  for (int tt = 0; tt < 6; ++tt) {
    if (tt < nch) {
#pragma unroll
      for (int q = 0; q < 4; ++q) *(i32x4*)(myl + wofs[q]) = gb[tt & 1][q];
      if (tt + 2 < 6 && tt + 2 < nch) AGG_ISSUE(tt + 2, tt & 1);
      asm volatile("s_waitcnt lgkmcnt(0)" ::: "memory");
      agg_chunk_compute(trbase, cb + tt * 32, lo, span, quad, acc);
    }
  }
  for (int t = 6; t < nch; ++t) {
    const int pos = min(cb + t * 32 + e32, E - 1);
    const int idx = edgeSrc[pos];
    const unsigned short* rp = proj + (size_t)idx * 64 + p * 32;
    i32x4 g4[4];
    g4[0] = *(const i32x4*)(rp);
    g4[1] = *(const i32x4*)(rp + 8);
    g4[2] = *(const i32x4*)(rp + 16);
    g4[3] = *(const i32x4*)(rp + 24);
#pragma unroll
    for (int q = 0; q < 4; ++q) *(i32x4*)(myl + wofs[q]) = g4[q];
    asm volatile("s_waitcnt lgkmcnt(0)" ::: "memory");
    agg_chunk_compute(trbase, cb + t * 32, lo, span, quad, acc);
  }
#undef AGG_ISSUE

  // ---- epilogue: finalize -> stage[w] -> coalesced stores (kills 2B-store RMW) ----
  if (LAST && !isb) {
    float* fs = (float*)myl;
#pragma unroll
    for (int reg = 0; reg < 4; ++reg) {
      const int row = quad * 4 + reg;
      if (row < 8) {
        const int node = min(g0 + row, N - 1);
        const float nd = norm_dst[node];
#pragma unroll
        for (int nt = 0; nt < 4; ++nt)
          fs[row * 64 + nt * 16 + l16] = fmaxf(fmaf(acc[nt][reg], nd, bcol[nt]), 0.f);
      }
    }
    asm volatile("s_waitcnt lgkmcnt(0)" ::: "memory");
    __builtin_amdgcn_sched_barrier(0);
    const int r = lane >> 3;
    const int c0 = (lane & 7) * 8;
    const int node = g0 + r;
    if (node < N) {
      const float4 v0 = *(const float4*)&fs[r * 64 + c0];
      const float4 v1 = *(const float4*)&fs[r * 64 + c0 + 4];
      float* of = (float*)outp + (size_t)node * 64 + c0;
      *(float4*)of = v0;
      *(float4*)(of + 4) = v1;
    }
  } else {
#pragma unroll
    for (int reg = 0; reg < 4; ++reg) {
      const int row = quad * 4 + reg;
      if (row < 8) {
        const int node = min(g0 + row, N - 1);
        const float nd = norm_dst[node];
        const float esc = LAST ? 1.f : norm_src[node];
#pragma unroll
        for (int nt = 0; nt < 4; ++nt) {
          float x = fmaxf(fmaf(acc[nt][reg], nd, bcol[nt]), 0.f);
          if (!LAST) x *= esc;
          myl[row * 64 + nt * 16 + l16] = f2b(x);
        }
      }
    }
    asm volatile("s_waitcnt lgkmcnt(0)" ::: "memory");
    __builtin_amdgcn_sched_barrier(0);
    if (lane < 32) {
      const int r = lane >> 2;
      const int c0 = (lane & 3) * 16;
      const int node = g0 + r;
      if (node < N) {
        const u16x8 v0 = *(const u16x8*)&myl[r * 64 + c0];
        const u16x8 v1 = *(const u16x8*)&myl[r * 64 + c0 + 8];
        *(u16x8*)((unsigned short*)outp + (size_t)node * 64 + c0) = v0;
        *(u16x8*)((unsigned short*)outp + (size_t)node * 64 + c0 + 8) = v1;
      }
    }
  }
}

extern "C" void kernel_launch(void* const* d_in, const int* in_sizes, int n_in,
                              void* d_out, int out_size, void* d_ws, size_t ws_size,
                              hipStream_t stream) {
  const void* features = d_in[0];
  const void* W0 = d_in[1];
  const void* b0 = d_in[2];
  const void* W1 = d_in[3];
  const void* b1 = d_in[4];
  const void* W2 = d_in[5];
  const void* b2 = d_in[6];
  const int* src = (const int*)d_in[7];
  const int* dst = (const int*)d_in[8];
  const int N = in_sizes[0] / 128;
  const int E = in_sizes[7];
  const int NBUCK = (N + 255) >> 8;
  const int M = NBUCK * 256;
  const int M2 = 2 * M;

  char* w = (char*)d_ws;
  size_t off = 0;
  auto alloc = [&](size_t bytes) {
    void* p = w + off;
    off = (off + bytes + 255) & ~(size_t)255;
    return p;
  };
  int* flag = (int*)alloc(4);
  int* rowStart = (int*)alloc((size_t)(N + 1) * 4);
  int* counts = (int*)alloc((size_t)M2 * 4);
  int* bsums = (int*)alloc(1024 * 4);
  float* norm_src = (float*)alloc((size_t)N * 4);
  float* norm_dst = (float*)alloc((size_t)N * 4);
  int* tmp = (int*)alloc((size_t)E * 4);
  unsigned char* tmp2 = (unsigned char*)alloc((size_t)E);
  int* edgeSrc = (int*)alloc((size_t)E * 4);
  unsigned short* projA = (unsigned short*)alloc((size_t)N * 64 * 2);  // bf16
  unsigned short* hB = (unsigned short*)d_out;  // inter-layer h (bf16) in d_out

  const size_t lds_nb = (size_t)NBUCK * 2 * 4;  // dual hist/cursors
  const int G16 = (N + 15) / 16;                // 16-row groups
  const int GB = (G16 + 7) / 8;                 // exactly 2 groups per wave, balanced

  // CSR build — zero global atomics end-to-end, no memset needed.
  k_passA<<<257, 256, lds_nb, stream>>>(src, dst, E, NBUCK, M, counts,
                                        (const unsigned short*)features, flag);
  const int NB2 = (M2 + 255) / 256;  // == 2*NBUCK
  k_scan1<<<NB2, 256, 0, stream>>>(counts, M2, bsums);
  k_scan2<<<1, 1024, 0, stream>>>(bsums, NB2, rowStart, N, E);
  k_scan3<<<NB2, 256, 0, stream>>>(counts, M2, bsums);
  k_passC<<<256, 256, lds_nb, stream>>>(src, dst, E, NBUCK, M, counts, tmp, tmp2);
  k_passD<<<NBUCK, 256, 0, stream>>>(tmp, tmp2, counts, NBUCK, M, N, E,
                                     rowStart, edgeSrc, norm_src, norm_dst);

  const int AB = (((N + 7) / 8) + 3) / 4;  // 8 nodes/wave, 4 waves/block
  // layer 0 (ns folded into gemm0 epilogue)
  k_gemm<128, true, true><<<GB, 256, 0, stream>>>(features, W0, flag, norm_src, N, projA);
  k_aggregate<false><<<AB, 256, 0, stream>>>(projA, edgeSrc, rowStart, norm_dst, norm_src, b0, flag, N, E, hB);
  // layer 1 (h pre-scaled by ns in agg epilogue)
  k_gemm<64, false, false><<<GB, 256, 0, stream>>>(hB, W1, flag, nullptr, N, projA);
  k_aggregate<false><<<AB, 256, 0, stream>>>(projA, edgeSrc, rowStart, norm_dst, norm_src, b1, flag, N, E, hB);
  // layer 2 -> d_out
  k_gemm<64, false, false><<<GB, 256, 0, stream>>>(hB, W2, flag, nullptr, N, projA);
  k_aggregate<true><<<AB, 256, 0, stream>>>(projA, edgeSrc, rowStart, norm_dst, norm_src, b2, flag, N, E, d_out);
}

// Round 7
// 300.243 us; speedup vs baseline: 1.1905x; 1.0506x over previous
//
#include <hip/hip_runtime.h>
#include <hip/hip_bf16.h>

typedef __hip_bfloat16 bf16;
typedef __attribute__((ext_vector_type(8))) short bf16x8;
typedef __attribute__((ext_vector_type(8))) unsigned short u16x8;
typedef __attribute__((ext_vector_type(4))) float f32x4;
typedef __attribute__((ext_vector_type(4))) int i32x4;
typedef __attribute__((ext_vector_type(4))) short s16x4;

__device__ __forceinline__ float b2f(unsigned short u) {
  return __uint_as_float(((unsigned)u) << 16);
}
__device__ __forceinline__ unsigned short f2b(float x) {
  bf16 h = __float2bfloat16(x);
  return *reinterpret_cast<unsigned short*>(&h);
}

// ============== passA: coarse hist of dst AND src + dtype probe ==============
__global__ void k_passA(const int* __restrict__ src, const int* __restrict__ dst, int E,
                        int nbuck, int M, int* __restrict__ counts,
                        const unsigned short* __restrict__ raw, int* __restrict__ flag) {
  if (blockIdx.x == 256) {
    __shared__ int sbad, snz;
    const int t = threadIdx.x;
    if (t == 0) { sbad = 0; snz = 0; }
    __syncthreads();
    const unsigned short u = raw[t];
    const float a = fabsf(b2f(u));
    if (!(a < 100.f)) atomicAdd(&sbad, 1);
    if (((t & 1) == 0) && u != 0) atomicAdd(&snz, 1);
    __syncthreads();
    if (t == 0) flag[0] = (sbad == 0 && snz > 0) ? 1 : 0;
    return;
  }
  extern __shared__ int lh[];  // lh1[nbuck] then lh2[nbuck]
  int* lh1 = lh;
  int* lh2 = lh + nbuck;
  const int t = threadIdx.x;
  for (int k = t; k < 2 * nbuck; k += 256) lh[k] = 0;
  __syncthreads();
  const int chunk = (E + 255) / 256;
  const int s = blockIdx.x * chunk;
  const int e = min(E, s + chunk);
  for (int i = s + t; i < e; i += 256) {
    atomicAdd(&lh1[dst[i] >> 8], 1);
    atomicAdd(&lh2[src[i] >> 8], 1);
  }
  __syncthreads();
  for (int k = t; k < nbuck; k += 256) {
    counts[k * 256 + blockIdx.x] = lh1[k];
    counts[M + k * 256 + blockIdx.x] = lh2[k];
  }
}

// exclusive scan over 2M ints
__global__ void k_scan1(const int* __restrict__ a, int M2, int* __restrict__ bsums) {
  __shared__ int sdata[256];
  int i = blockIdx.x * 256 + threadIdx.x;
  int v = (i < M2) ? a[i] : 0;
  sdata[threadIdx.x] = v;
  __syncthreads();
  for (int s = 128; s > 0; s >>= 1) {
    if (threadIdx.x < s) sdata[threadIdx.x] += sdata[threadIdx.x + s];
    __syncthreads();
  }
  if (threadIdx.x == 0) bsums[blockIdx.x] = sdata[0];
}

__global__ void k_scan2(int* __restrict__ bsums, int nb, int* __restrict__ rowStart,
                        int N, int E) {
  __shared__ int s[1024];
  const int t = threadIdx.x;
  const int v = (t < nb) ? bsums[t] : 0;
  s[t] = v;
  __syncthreads();
  for (int off = 1; off < 1024; off <<= 1) {
    int u = (t >= off) ? s[t - off] : 0;
    __syncthreads();
    s[t] += u;
    __syncthreads();
  }
  if (t < nb) bsums[t] = s[t] - v;  // exclusive
  if (t == 0) rowStart[N] = E;
}

__global__ void k_scan3(int* __restrict__ a, int M2, const int* __restrict__ bsums) {
  __shared__ int sdata[256];
  int i = blockIdx.x * 256 + threadIdx.x;
  int v = (i < M2) ? a[i] : 0;
  sdata[threadIdx.x] = v;
  __syncthreads();
  for (int off = 1; off < 256; off <<= 1) {
    int t = (threadIdx.x >= off) ? sdata[threadIdx.x - off] : 0;
    __syncthreads();
    sdata[threadIdx.x] += t;
    __syncthreads();
  }
  if (i < M2) a[i] = bsums[blockIdx.x] + sdata[threadIdx.x] - v;  // exclusive
}

// passC: dual scatter via LDS cursors — ZERO global atomics.
__global__ void k_passC(const int* __restrict__ src, const int* __restrict__ dst, int E,
                        int nbuck, int M, const int* __restrict__ S,
                        int* __restrict__ tmp, unsigned char* __restrict__ tmp2) {
  extern __shared__ int cur[];  // cur1[nbuck], cur2[nbuck]
  int* cur1 = cur;
  int* cur2 = cur + nbuck;
  const int t = threadIdx.x;
  for (int k = t; k < nbuck; k += 256) {
    cur1[k] = S[k * 256 + blockIdx.x];
    cur2[k] = S[M + k * 256 + blockIdx.x];
  }
  __syncthreads();
  const int chunk = (E + 255) / 256;
  const int s = blockIdx.x * chunk;
  const int e = min(E, s + chunk);
  for (int i = s + t; i < e; i += 256) {
    const int sv = src[i];
    const int d = dst[i];
    const int pos1 = atomicAdd(&cur1[d >> 8], 1);
    tmp[pos1] = sv | ((d & 255) << 20);
    const int pos2 = atomicAdd(&cur2[sv >> 8], 1);
    tmp2[pos2 - E] = (unsigned char)(sv & 255);
  }
}

// passD: per bucket k: (1) src-side byte hist -> deg_out -> ns;
//        (2) dst-side hist + scan -> rowStart, nd, edgeSrc scatter.
__global__ void k_passD(const int* __restrict__ tmp, const unsigned char* __restrict__ tmp2,
                        const int* __restrict__ S, int nbuck, int M, int N, int E,
                        int* __restrict__ rowStart, int* __restrict__ edgeSrc,
                        float* __restrict__ ns, float* __restrict__ nd) {
  __shared__ int h[256];
  __shared__ int ex[256];
  __shared__ int c[256];
  const int t = threadIdx.x;
  const int k = blockIdx.x;
  const int node = k * 256 + t;
  const int bs2 = S[M + k * 256] - E;
  const int be2 = (k + 1 < nbuck) ? (S[M + (k + 1) * 256] - E) : E;
  h[t] = 0;
  __syncthreads();
  for (int i = bs2 + t; i < be2; i += 256) atomicAdd(&h[tmp2[i]], 1);
  __syncthreads();
  if (node < N) {
    int dov = h[t];
    if (dov <= 0) dov = 1;
    ns[node] = rsqrtf((float)dov);
  }
  __syncthreads();
  const int bs = S[k * 256];
  const int be = (k + 1 < nbuck) ? S[(k + 1) * 256] : E;
  h[t] = 0;
  __syncthreads();
  for (int i = bs + t; i < be; i += 256) atomicAdd(&h[tmp[i] >> 20], 1);
  __syncthreads();
  const int cnt = h[t];
  ex[t] = cnt;
  __syncthreads();
  for (int off = 1; off < 256; off <<= 1) {
    int u = (t >= off) ? ex[t - off] : 0;
    __syncthreads();
    ex[t] += u;
    __syncthreads();
  }
  const int excl = ex[t] - cnt;
  if (node < N) {
    rowStart[node] = bs + excl;
    nd[node] = rsqrtf((float)(cnt > 0 ? cnt : 1));
  }
  c[t] = bs + excl;
  __syncthreads();
  for (int i = bs + t; i < be; i += 256) {
    const int v = tmp[i];
    const int pos = atomicAdd(&c[v >> 20], 1);
    edgeSrc[pos] = v & 0xFFFFF;
  }
}

// ---------------- MFMA GEMM layer-0 (LDS-staged W + A-prefetch + vectorized C) -------
template <int K, bool FIRST, bool SCALE>
__device__ __forceinline__ void gemm_loadA(const void* hin, bool isb, int rowA,
                                           int quad, bf16x8* A) {
  constexpr int KT = K / 32;
  if (FIRST && !isb) {
    const float* hp = (const float*)hin + (size_t)rowA * K;
#pragma unroll
    for (int kt = 0; kt < KT; ++kt) {
      const float4 u0 = *(const float4*)(hp + kt * 32 + quad * 8);
      const float4 u1 = *(const float4*)(hp + kt * 32 + quad * 8 + 4);
      A[kt][0] = (short)f2b(u0.x); A[kt][1] = (short)f2b(u0.y);
      A[kt][2] = (short)f2b(u0.z); A[kt][3] = (short)f2b(u0.w);
      A[kt][4] = (short)f2b(u1.x); A[kt][5] = (short)f2b(u1.y);
      A[kt][6] = (short)f2b(u1.z); A[kt][7] = (short)f2b(u1.w);
    }
  } else {
    const unsigned short* hp = (const unsigned short*)hin + (size_t)rowA * K;
#pragma unroll
    for (int kt = 0; kt < KT; ++kt)
      A[kt] = *(const bf16x8*)(hp + kt * 32 + quad * 8);
  }
}

template <int K, bool FIRST, bool SCALE>
__global__ void __launch_bounds__(256) k_gemm(
    const void* __restrict__ hin, const void* __restrict__ Wv,
    const int* __restrict__ flag, const float* __restrict__ norm_src,
    int N, unsigned short* __restrict__ out) {
  constexpr int KT = K / 32;
  constexpr int ST = K + 8;     // W-tile row stride (shorts)
  constexpr int CST = 72;       // C-tile row stride (shorts)
  __shared__ unsigned short Wl[64 * ST];
  __shared__ unsigned short Cl[4][16 * CST];
  const bool isb = (*flag != 0);
  const int tid = threadIdx.x;

  {
    const unsigned short* Wus = (const unsigned short*)Wv;
    const float* Wf = (const float*)Wv;
    for (int i0 = tid * 8; i0 < K * 64; i0 += 2048) {
      const int k = i0 >> 6;
      const int n0 = i0 & 63;
      unsigned short v[8];
      if (isb) {
        const u16x8 u = *(const u16x8*)(Wus + i0);
#pragma unroll
        for (int j = 0; j < 8; ++j) v[j] = u[j];
      } else {
        const float4 f0 = *(const float4*)(Wf + i0);
        const float4 f1 = *(const float4*)(Wf + i0 + 4);
        v[0] = f2b(f0.x); v[1] = f2b(f0.y); v[2] = f2b(f0.z); v[3] = f2b(f0.w);
        v[4] = f2b(f1.x); v[5] = f2b(f1.y); v[6] = f2b(f1.z); v[7] = f2b(f1.w);
      }
#pragma unroll
      for (int j = 0; j < 8; ++j) Wl[(n0 + j) * ST + k] = v[j];
    }
  }
  __syncthreads();

  const int lane = tid & 63;
  const int quad = lane >> 4;
  const int l16 = lane & 15;
  const int w = tid >> 6;
  unsigned short* myC = &Cl[w][0];

  const int wid = blockIdx.x * 4 + w;
  const int nw = gridDim.x * 4;
  const int G = (N + 15) >> 4;

  bf16x8 A0[KT], A1[KT];
  if (wid < G) {
    int r0 = (wid << 4) + l16;
    if (r0 >= N) r0 = N - 1;
    gemm_loadA<K, FIRST, SCALE>(hin, isb, r0, quad, A0);
  }
  for (int g = wid; g < G; g += nw) {
    if (g + nw < G) {
      int r1 = ((g + nw) << 4) + l16;
      if (r1 >= N) r1 = N - 1;
      gemm_loadA<K, FIRST, SCALE>(hin, isb, r1, quad, A1);
    }
    f32x4 acc[4] = {{0.f, 0.f, 0.f, 0.f}, {0.f, 0.f, 0.f, 0.f},
                    {0.f, 0.f, 0.f, 0.f}, {0.f, 0.f, 0.f, 0.f}};
#pragma unroll
    for (int kt = 0; kt < KT; ++kt) {
      const int koff = kt * 32 + quad * 8;
#pragma unroll
      for (int nt = 0; nt < 4; ++nt) {
        const bf16x8 Bf = *(const bf16x8*)&Wl[(nt * 16 + l16) * ST + koff];
        acc[nt] = __builtin_amdgcn_mfma_f32_16x16x32_bf16(A0[kt], Bf, acc[nt], 0, 0, 0);
      }
    }
    const int rowD = quad * 4;
#pragma unroll
    for (int r = 0; r < 4; ++r) {
      const int nodeW = (g << 4) + rowD + r;
      const float f = (SCALE && nodeW < N) ? norm_src[nodeW] : 1.0f;
#pragma unroll
      for (int nt = 0; nt < 4; ++nt)
        myC[(rowD + r) * CST + nt * 16 + l16] = f2b(SCALE ? acc[nt][r] * f : acc[nt][r]);
    }
    const int row2 = lane >> 2;
    const int c0 = (lane & 3) * 16;
    const int node = (g << 4) + row2;
    if (node < N) {
      const u16x8 v0 = *(const u16x8*)&myC[row2 * CST + c0];
      const u16x8 v1 = *(const u16x8*)&myC[row2 * CST + c0 + 8];
      *(u16x8*)(out + (size_t)node * 64 + c0) = v0;
      *(u16x8*)(out + (size_t)node * 64 + c0 + 8) = v1;
    }
#pragma unroll
    for (int kt = 0; kt < KT; ++kt) A0[kt] = A1[kt];
  }
}

// ---------------- MFMA aggregation (SpMM, segment-indicator A) + fused next-gemm -----
__device__ __forceinline__ void agg_chunk_compute(unsigned trbase, int cb32, int lo,
                                                  unsigned span, int quad, f32x4* acc) {
  const int posbase = cb32 + (quad << 2);
  const unsigned u0 = (unsigned)(posbase - lo);
  bf16x8 Af;
#pragma unroll
  for (int j = 0; j < 8; ++j) {
    const unsigned off = (j < 4) ? (unsigned)j : (unsigned)(12 + j);
    Af[j] = ((u0 + off) < span) ? (short)0x3F80 : (short)0;
  }
  s16x4 t0[4], t1[4];
#pragma unroll
  for (int nt = 0; nt < 4; ++nt) {
    const unsigned a = trbase + (unsigned)(nt * 1024);
    asm volatile("ds_read_b64_tr_b16 %0, %1" : "=v"(t0[nt]) : "v"(a) : "memory");
    asm volatile("ds_read_b64_tr_b16 %0, %1 offset:512" : "=v"(t1[nt]) : "v"(a) : "memory");
  }
  asm volatile("s_waitcnt lgkmcnt(0)" ::: "memory");
  __builtin_amdgcn_sched_barrier(0);
#pragma unroll
  for (int nt = 0; nt < 4; ++nt) {
    bf16x8 Bf;
    Bf[0] = t0[nt][0]; Bf[1] = t0[nt][1]; Bf[2] = t0[nt][2]; Bf[3] = t0[nt][3];
    Bf[4] = t1[nt][0]; Bf[5] = t1[nt][1]; Bf[6] = t1[nt][2]; Bf[7] = t1[nt][3];
    acc[nt] = __builtin_amdgcn_mfma_f32_16x16x32_bf16(Af, Bf, acc[nt], 0, 0, 0);
  }
}

// FUSE: epilogue computes h=relu(agg*nd+b)*ns into a block LDS tile, then the block's
// 4 waves cooperatively compute proj = h @ Wnext (W LDS-staged) and store bf16 16B.
template <bool LAST, bool FUSE>
__global__ void __launch_bounds__(256) k_aggregate(
    const unsigned short* __restrict__ proj,
    const int* __restrict__ edgeSrc, const int* __restrict__ rowStart,
    const float* __restrict__ norm_dst, const float* __restrict__ norm_src,
    const void* __restrict__ bias, const int* __restrict__ flag,
    const void* __restrict__ Wv, int N, int E, void* __restrict__ outp) {
  __shared__ unsigned short lds[4][2048];  // 4 KB per wave: [32 edges][64 cols]
  const bool isb = (*flag != 0);
  const int tid = threadIdx.x;
  const int w = tid >> 6;
  const int lane = tid & 63;
  const int l16 = lane & 15;
  const int quad = lane >> 4;
  const int e32 = lane & 31;
  const int p = lane >> 5;

  const int wid = blockIdx.x * 4 + w;
  const int g0 = wid * 8;

  float bcol[4];
#pragma unroll
  for (int nt = 0; nt < 4; ++nt) {
    const int col = nt * 16 + l16;
    bcol[nt] = isb ? b2f(((const unsigned short*)bias)[col]) : ((const float*)bias)[col];
  }

  const int cb = rowStart[min(g0, N)];
  const int ce = rowStart[min(g0 + 8, N)];
  const int L = ce - cb;
  const int nch = (L + 31) >> 5;

  const int rsi = min(g0 + min(l16, 8), N);
  const int rsj = min(g0 + min(l16 + 1, 8), N);
  const int lo = rowStart[rsi];
  const unsigned span = (unsigned)(rowStart[rsj] - lo);

  int idxc[6];
#pragma unroll
  for (int t = 0; t < 6; ++t) {
    const int pos = min(cb + t * 32 + e32, E - 1);
    idxc[t] = edgeSrc[pos];
  }

  unsigned short* myl = &lds[w][0];
  unsigned wofs[4];
#pragma unroll
  for (int q = 0; q < 4; ++q) {
    const int n0 = p * 32 + q * 8;
    wofs[q] = (unsigned)((n0 >> 4) * 512 + e32 * 16 + (n0 & 15));
  }
  const unsigned trbase = (unsigned)(uintptr_t)myl + (unsigned)lane * 8u;

  f32x4 acc[4] = {{0.f, 0.f, 0.f, 0.f}, {0.f, 0.f, 0.f, 0.f},
                  {0.f, 0.f, 0.f, 0.f}, {0.f, 0.f, 0.f, 0.f}};

  i32x4 gb[2][4];
#define AGG_ISSUE(t, b)                                                         \
  {                                                                             \
    const unsigned short* rp = proj + (size_t)idxc[t] * 64 + p * 32;            \
    gb[b][0] = *(const i32x4*)(rp);                                             \
    gb[b][1] = *(const i32x4*)(rp + 8);                                         \
    gb[b][2] = *(const i32x4*)(rp + 16);                                        \
    gb[b][3] = *(const i32x4*)(rp + 24);                                        \
  }
  if (0 < nch) AGG_ISSUE(0, 0);
  if (1 < nch) AGG_ISSUE(1, 1);

#pragma unroll
  for (int tt = 0; tt < 6; ++tt) {
    if (tt < nch) {
#pragma unroll
      for (int q = 0; q < 4; ++q) *(i32x4*)(myl + wofs[q]) = gb[tt & 1][q];
      if (tt + 2 < 6 && tt + 2 < nch) AGG_ISSUE(tt + 2, tt & 1);
      asm volatile("s_waitcnt lgkmcnt(0)" ::: "memory");
      agg_chunk_compute(trbase, cb + tt * 32, lo, span, quad, acc);
    }
  }
  for (int t = 6; t < nch; ++t) {
    const int pos = min(cb + t * 32 + e32, E - 1);
    const int idx = edgeSrc[pos];
    const unsigned short* rp = proj + (size_t)idx * 64 + p * 32;
    i32x4 g4[4];
    g4[0] = *(const i32x4*)(rp);
    g4[1] = *(const i32x4*)(rp + 8);
    g4[2] = *(const i32x4*)(rp + 16);
    g4[3] = *(const i32x4*)(rp + 24);
#pragma unroll
    for (int q = 0; q < 4; ++q) *(i32x4*)(myl + wofs[q]) = g4[q];
    asm volatile("s_waitcnt lgkmcnt(0)" ::: "memory");
    agg_chunk_compute(trbase, cb + t * 32, lo, span, quad, acc);
  }
#undef AGG_ISSUE

  if constexpr (FUSE) {
    // ---- fused epilogue: h -> block LDS tile -> h @ Wnext -> proj stores ----
    __shared__ unsigned short hT[32 * 72];   // block h tile, 144B row stride (16B-aligned)
    __shared__ unsigned short Wl2[64 * 72];  // Wnext transposed [n][k]
    {
      const unsigned short* Wus = (const unsigned short*)Wv;
      const float* Wf = (const float*)Wv;
      for (int i0 = tid * 8; i0 < 64 * 64; i0 += 2048) {
        const int k = i0 >> 6;
        const int n0 = i0 & 63;
        unsigned short v[8];
        if (isb) {
          const u16x8 u = *(const u16x8*)(Wus + i0);
#pragma unroll
          for (int j = 0; j < 8; ++j) v[j] = u[j];
        } else {
          const float4 f0 = *(const float4*)(Wf + i0);
          const float4 f1 = *(const float4*)(Wf + i0 + 4);
          v[0] = f2b(f0.x); v[1] = f2b(f0.y); v[2] = f2b(f0.z); v[3] = f2b(f0.w);
          v[4] = f2b(f1.x); v[5] = f2b(f1.y); v[6] = f2b(f1.z); v[7] = f2b(f1.w);
        }
#pragma unroll
        for (int j = 0; j < 8; ++j) Wl2[(n0 + j) * 72 + k] = v[j];
      }
    }
#pragma unroll
    for (int reg = 0; reg < 4; ++reg) {
      const int row = quad * 4 + reg;
      if (row < 8) {
        const int node = min(g0 + row, N - 1);
        const float nd = norm_dst[node];
        const float esc = norm_src[node];
#pragma unroll
        for (int nt = 0; nt < 4; ++nt) {
          const float x = fmaxf(fmaf(acc[nt][reg], nd, bcol[nt]), 0.f) * esc;
          hT[(w * 8 + row) * 72 + nt * 16 + l16] = f2b(x);
        }
      }
    }
    __syncthreads();
    // each wave: 16 rows x 32 cols of proj = h @ W
    const int r0 = (w & 1) * 16;
    const int cb2 = (w >> 1) * 32;
    bf16x8 Afr[2], Bfr[2][2];
#pragma unroll
    for (int kt = 0; kt < 2; ++kt) {
      const int koff = kt * 32 + quad * 8;
      Afr[kt] = *(const bf16x8*)&hT[(r0 + l16) * 72 + koff];
#pragma unroll
      for (int nt = 0; nt < 2; ++nt)
        Bfr[kt][nt] = *(const bf16x8*)&Wl2[(cb2 + nt * 16 + l16) * 72 + koff];
    }
    f32x4 acc2[2] = {{0.f, 0.f, 0.f, 0.f}, {0.f, 0.f, 0.f, 0.f}};
#pragma unroll
    for (int kt = 0; kt < 2; ++kt)
#pragma unroll
      for (int nt = 0; nt < 2; ++nt)
        acc2[nt] = __builtin_amdgcn_mfma_f32_16x16x32_bf16(Afr[kt], Bfr[kt][nt], acc2[nt], 0, 0, 0);
    __syncthreads();  // all A/B LDS reads complete before hT is overwritten
#pragma unroll
    for (int nt = 0; nt < 2; ++nt)
#pragma unroll
      for (int reg = 0; reg < 4; ++reg) {
        const int row = r0 + quad * 4 + reg;
        hT[row * 72 + cb2 + nt * 16 + l16] = f2b(acc2[nt][reg]);
      }
    __syncthreads();
    const int row = tid >> 3;
    const int c0 = (tid & 7) * 8;
    const int node = blockIdx.x * 32 + row;
    if (node < N) {
      *(u16x8*)((unsigned short*)outp + (size_t)node * 64 + c0) =
          *(const u16x8*)&hT[row * 72 + c0];
    }
  } else {
    // ---- LAST epilogue: finalize -> stage[w] -> coalesced stores ----
    if (!isb) {
      float* fs = (float*)myl;
#pragma unroll
      for (int reg = 0; reg < 4; ++reg) {
        const int row = quad * 4 + reg;
        if (row < 8) {
          const int node = min(g0 + row, N - 1);
          const float nd = norm_dst[node];
#pragma unroll
          for (int nt = 0; nt < 4; ++nt)
            fs[row * 64 + nt * 16 + l16] = fmaxf(fmaf(acc[nt][reg], nd, bcol[nt]), 0.f);
        }
      }
      asm volatile("s_waitcnt lgkmcnt(0)" ::: "memory");
      __builtin_amdgcn_sched_barrier(0);
      const int r = lane >> 3;
      const int c0 = (lane & 7) * 8;
      const int node = g0 + r;
      if (node < N) {
        const float4 v0 = *(const float4*)&fs[r * 64 + c0];
        const float4 v1 = *(const float4*)&fs[r * 64 + c0 + 4];
        float* of = (float*)outp + (size_t)node * 64 + c0;
        *(float4*)of = v0;
        *(float4*)(of + 4) = v1;
      }
    } else {
#pragma unroll
      for (int reg = 0; reg < 4; ++reg) {
        const int row = quad * 4 + reg;
        if (row < 8) {
          const int node = min(g0 + row, N - 1);
          const float nd = norm_dst[node];
#pragma unroll
          for (int nt = 0; nt < 4; ++nt) {
            const float x = fmaxf(fmaf(acc[nt][reg], nd, bcol[nt]), 0.f);
            myl[row * 64 + nt * 16 + l16] = f2b(x);
          }
        }
      }
      asm volatile("s_waitcnt lgkmcnt(0)" ::: "memory");
      __builtin_amdgcn_sched_barrier(0);
      if (lane < 32) {
        const int r = lane >> 2;
        const int c0 = (lane & 3) * 16;
        const int node = g0 + r;
        if (node < N) {
          const u16x8 v0 = *(const u16x8*)&myl[r * 64 + c0];
          const u16x8 v1 = *(const u16x8*)&myl[r * 64 + c0 + 8];
          *(u16x8*)((unsigned short*)outp + (size_t)node * 64 + c0) = v0;
          *(u16x8*)((unsigned short*)outp + (size_t)node * 64 + c0 + 8) = v1;
        }
      }
    }
  }
}

extern "C" void kernel_launch(void* const* d_in, const int* in_sizes, int n_in,
                              void* d_out, int out_size, void* d_ws, size_t ws_size,
                              hipStream_t stream) {
  const void* features = d_in[0];
  const void* W0 = d_in[1];
  const void* b0 = d_in[2];
  const void* W1 = d_in[3];
  const void* b1 = d_in[4];
  const void* W2 = d_in[5];
  const void* b2 = d_in[6];
  const int* src = (const int*)d_in[7];
  const int* dst = (const int*)d_in[8];
  const int N = in_sizes[0] / 128;
  const int E = in_sizes[7];
  const int NBUCK = (N + 255) >> 8;
  const int M = NBUCK * 256;
  const int M2 = 2 * M;

  char* w = (char*)d_ws;
  size_t off = 0;
  auto alloc = [&](size_t bytes) {
    void* p = w + off;
    off = (off + bytes + 255) & ~(size_t)255;
    return p;
  };
  int* flag = (int*)alloc(4);
  int* rowStart = (int*)alloc((size_t)(N + 1) * 4);
  int* counts = (int*)alloc((size_t)M2 * 4);
  int* bsums = (int*)alloc(1024 * 4);
  float* norm_src = (float*)alloc((size_t)N * 4);
  float* norm_dst = (float*)alloc((size_t)N * 4);
  int* tmp = (int*)alloc((size_t)E * 4);
  unsigned char* tmp2 = (unsigned char*)alloc((size_t)E);
  int* edgeSrc = (int*)alloc((size_t)E * 4);
  unsigned short* projA = (unsigned short*)alloc((size_t)N * 64 * 2);  // bf16
  unsigned short* projB = (unsigned short*)alloc((size_t)N * 64 * 2);  // bf16

  const size_t lds_nb = (size_t)NBUCK * 2 * 4;  // dual hist/cursors
  const int GB = 1024;

  // CSR build — zero global atomics end-to-end, no memset needed.
  k_passA<<<257, 256, lds_nb, stream>>>(src, dst, E, NBUCK, M, counts,
                                        (const unsigned short*)features, flag);
  const int NB2 = (M2 + 255) / 256;  // == 2*NBUCK
  k_scan1<<<NB2, 256, 0, stream>>>(counts, M2, bsums);
  k_scan2<<<1, 1024, 0, stream>>>(bsums, NB2, rowStart, N, E);
  k_scan3<<<NB2, 256, 0, stream>>>(counts, M2, bsums);
  k_passC<<<256, 256, lds_nb, stream>>>(src, dst, E, NBUCK, M, counts, tmp, tmp2);
  k_passD<<<NBUCK, 256, 0, stream>>>(tmp, tmp2, counts, NBUCK, M, N, E,
                                     rowStart, edgeSrc, norm_src, norm_dst);

  const int AB = (((N + 7) / 8) + 3) / 4;  // 8 nodes/wave, 4 waves/block (32/block)
  // layer 0 gemm (ns folded into epilogue)
  k_gemm<128, true, true><<<GB, 256, 0, stream>>>(features, W0, flag, norm_src, N, projA);
  // agg0 + fused gemm1 -> projB
  k_aggregate<false, true><<<AB, 256, 0, stream>>>(projA, edgeSrc, rowStart, norm_dst,
                                                   norm_src, b0, flag, W1, N, E, projB);
  // agg1 + fused gemm2 -> projA
  k_aggregate<false, true><<<AB, 256, 0, stream>>>(projB, edgeSrc, rowStart, norm_dst,
                                                   norm_src, b1, flag, W2, N, E, projA);
  // agg2 (LAST) -> d_out
  k_aggregate<true, false><<<AB, 256, 0, stream>>>(projA, edgeSrc, rowStart, norm_dst,
                                                   norm_src, b2, flag, nullptr, N, E, d_out);
}